// Round 3
// baseline (1688.352 us; speedup 1.0000x reference)
//
#include <hip/hip_runtime.h>

#define C_IN     256
#define C_OUT    512
#define M_PTS    25000
#define KNN      16
#define P_BLK    4
#define ROWS     (P_BLK * KNN)   /* 64 */
#define NTHREADS 256

__global__ __launch_bounds__(NTHREADS, 2)
void fused_fp32_diag(const float* __restrict__ x,
                     const int* __restrict__ idx,
                     const float* __restrict__ gamma,
                     const float* __restrict__ beta,
                     const float* __restrict__ W,
                     const float* __restrict__ bias,
                     float* __restrict__ out) {
    __shared__ float G[ROWS][C_IN];   // 64 KiB, fp32 LN output (no quantization)

    const int tid = threadIdx.x;
    const int m0  = blockIdx.x * P_BLK;

    // ---- Phase 1: gather + LayerNorm (IDENTICAL structure to the MFMA kernel) ----
    float gm[16], bt[16];
    const int cg = (tid & 15) * 16;
    #pragma unroll
    for (int q = 0; q < 4; ++q) {
        float4 g4 = ((const float4*)(gamma + cg))[q];
        float4 b4 = ((const float4*)(beta  + cg))[q];
        gm[4*q+0] = g4.x; gm[4*q+1] = g4.y; gm[4*q+2] = g4.z; gm[4*q+3] = g4.w;
        bt[4*q+0] = b4.x; bt[4*q+1] = b4.y; bt[4*q+2] = b4.z; bt[4*q+3] = b4.w;
    }
    #pragma unroll
    for (int it = 0; it < ROWS / 16; ++it) {
        const int r  = it * 16 + (tid >> 4);          // row: point (r>>4), neighbor (r&15)
        const int xr = idx[m0 * KNN + r];
        const float4* xp = (const float4*)(x + (size_t)xr * C_IN) + (tid & 15) * 4;
        float vv[16];
        float s = 0.f, sq = 0.f;
        #pragma unroll
        for (int q = 0; q < 4; ++q) {
            float4 v4 = xp[q];
            vv[4*q+0] = v4.x; vv[4*q+1] = v4.y; vv[4*q+2] = v4.z; vv[4*q+3] = v4.w;
        }
        #pragma unroll
        for (int e = 0; e < 16; ++e) { s += vv[e]; sq += vv[e]*vv[e]; }
        #pragma unroll
        for (int o = 1; o < 16; o <<= 1) {
            s  += __shfl_xor(s, o);
            sq += __shfl_xor(sq, o);
        }
        const float mu  = s * (1.0f/256.0f);
        const float var = sq * (1.0f/256.0f) - mu * mu;
        const float rs  = rsqrtf(var + 1e-5f);
        float4* gd = (float4*)(&G[r][cg]);
        #pragma unroll
        for (int q = 0; q < 4; ++q) {
            float4 o4;
            o4.x = (vv[4*q+0] - mu) * rs * gm[4*q+0] + bt[4*q+0];
            o4.y = (vv[4*q+1] - mu) * rs * gm[4*q+1] + bt[4*q+1];
            o4.z = (vv[4*q+2] - mu) * rs * gm[4*q+2] + bt[4*q+2];
            o4.w = (vv[4*q+3] - mu) * rs * gm[4*q+3] + bt[4*q+3];
            gd[q] = o4;
        }
    }
    __syncthreads();

    // ---- Phase 2: all-fp32 VALU GEMM + per-thread max-pool (diagnostic engine) ----
    const int p  = tid >> 6;            // wave id = point within block
    const int c0 = (tid & 63) * 8;      // this thread's 8 output channels
    float vmax[8];
    #pragma unroll
    for (int j = 0; j < 8; ++j) vmax[j] = -3.402823466e38f;

    #pragma unroll 1
    for (int ng = 0; ng < 4; ++ng) {    // neighbor groups of 4
        float acc[4][8];
        #pragma unroll
        for (int n = 0; n < 4; ++n)
            #pragma unroll
            for (int j = 0; j < 8; ++j) acc[n][j] = 0.f;

        #pragma unroll 2
        for (int i = 0; i < C_IN; ++i) {
            const float4 wa = *(const float4*)(W + (size_t)i * C_OUT + c0);
            const float4 wb = *(const float4*)(W + (size_t)i * C_OUT + c0 + 4);
            #pragma unroll
            for (int n = 0; n < 4; ++n) {
                const float gv = G[p * 16 + ng * 4 + n][i];   // wave-uniform broadcast
                acc[n][0] += gv * wa.x; acc[n][1] += gv * wa.y;
                acc[n][2] += gv * wa.z; acc[n][3] += gv * wa.w;
                acc[n][4] += gv * wb.x; acc[n][5] += gv * wb.y;
                acc[n][6] += gv * wb.z; acc[n][7] += gv * wb.w;
            }
        }
        #pragma unroll
        for (int n = 0; n < 4; ++n)
            #pragma unroll
            for (int j = 0; j < 8; ++j) vmax[j] = fmaxf(vmax[j], acc[n][j]);
    }

    float* op = out + (size_t)(m0 + p) * C_OUT + c0;
    #pragma unroll
    for (int j = 0; j < 8; ++j) op[j] = vmax[j] + bias[c0 + j];
}

extern "C" void kernel_launch(void* const* d_in, const int* in_sizes, int n_in,
                              void* d_out, int out_size, void* d_ws, size_t ws_size,
                              hipStream_t stream) {
    const float* x     = (const float*)d_in[0];
    const int*   idx   = (const int*)d_in[1];
    const float* gamma = (const float*)d_in[2];
    const float* beta  = (const float*)d_in[3];
    const float* W     = (const float*)d_in[4];
    const float* b     = (const float*)d_in[5];
    float* out = (float*)d_out;

    hipLaunchKernelGGL(fused_fp32_diag, dim3(M_PTS / P_BLK), dim3(NTHREADS), 0, stream,
                       x, idx, gamma, beta, W, b, out);
}

// Round 4
// 227.313 us; speedup vs baseline: 7.4274x; 7.4274x over previous
//
#include <hip/hip_runtime.h>

typedef _Float16 f16x8 __attribute__((ext_vector_type(8)));
typedef unsigned short ushort8 __attribute__((ext_vector_type(8)));
typedef float f32x4 __attribute__((ext_vector_type(4)));

#define C_IN     256
#define C_OUT    512
#define M_PTS    25000
#define KNN      16
#define P_BLK    4
#define ROWS     (P_BLK * KNN)   /* 64 */
#define ROWB     528             /* padded row stride in bytes (264 f16) */
#define NTHREADS 256

__global__ __launch_bounds__(NTHREADS, 3)
void fused_gather_ln_gemm_max(const float* __restrict__ x,
                              const int* __restrict__ idx,
                              const float* __restrict__ gamma,
                              const float* __restrict__ beta,
                              const float* __restrict__ W,
                              const float* __restrict__ bias,
                              float* __restrict__ out) {
    __shared__ char Ab[ROWS * ROWB];   // 33 KiB, f16 A-tile, padded rows, NO swizzle

    const int tid  = threadIdx.x;
    const int lane = tid & 63;
    const int wave = tid >> 6;
    const int m0   = blockIdx.x * P_BLK;

    // ---- Phase 1: gather + LayerNorm -> LDS (f16), identical math to the passing fp32 round ----
    float gm[16], bt[16];
    const int cg = (tid & 15) * 16;
    #pragma unroll
    for (int q = 0; q < 4; ++q) {
        float4 g4 = ((const float4*)(gamma + cg))[q];
        float4 b4 = ((const float4*)(beta  + cg))[q];
        gm[4*q+0] = g4.x; gm[4*q+1] = g4.y; gm[4*q+2] = g4.z; gm[4*q+3] = g4.w;
        bt[4*q+0] = b4.x; bt[4*q+1] = b4.y; bt[4*q+2] = b4.z; bt[4*q+3] = b4.w;
    }
    #pragma unroll
    for (int it = 0; it < ROWS / 16; ++it) {
        const int r  = it * 16 + (tid >> 4);
        const int xr = idx[m0 * KNN + r];
        const float4* xp = (const float4*)(x + (size_t)xr * C_IN) + (tid & 15) * 4;
        float vv[16];
        float s = 0.f, sq = 0.f;
        #pragma unroll
        for (int q = 0; q < 4; ++q) {
            float4 v4 = xp[q];
            vv[4*q+0] = v4.x; vv[4*q+1] = v4.y; vv[4*q+2] = v4.z; vv[4*q+3] = v4.w;
        }
        #pragma unroll
        for (int e = 0; e < 16; ++e) { s += vv[e]; sq += vv[e]*vv[e]; }
        #pragma unroll
        for (int o = 1; o < 16; o <<= 1) {
            s  += __shfl_xor(s, o);
            sq += __shfl_xor(sq, o);
        }
        const float mu  = s * (1.0f/256.0f);
        const float var = sq * (1.0f/256.0f) - mu * mu;
        const float rs  = rsqrtf(var + 1e-5f);
        ushort8 c0, c1;
        #pragma unroll
        for (int e = 0; e < 8; ++e) {
            _Float16 h = (_Float16)((vv[e]   - mu)*rs*gm[e]   + bt[e]);
            c0[e] = __builtin_bit_cast(unsigned short, h);
        }
        #pragma unroll
        for (int e = 0; e < 8; ++e) {
            _Float16 h = (_Float16)((vv[e+8] - mu)*rs*gm[e+8] + bt[e+8]);
            c1[e] = __builtin_bit_cast(unsigned short, h);
        }
        const int cb = (tid & 15) * 32;               // byte offset of channel group
        *(ushort8*)(Ab + r*ROWB + cb)      = c0;
        *(ushort8*)(Ab + r*ROWB + cb + 16) = c1;
    }
    __syncthreads();

    // ---- Phase 2: MFMA GEMM + fused max; W loaded DIRECTLY from global (no d_ws) ----
    #pragma unroll 1
    for (int ntp = 0; ntp < 4; ++ntp) {
        const int nt0 = wave * 8 + ntp * 2;
        const int nt1 = nt0 + 1;
        f16x8 b0[8], b1[8];
        #pragma unroll
        for (int kk = 0; kk < 8; ++kk) {
            #pragma unroll
            for (int j = 0; j < 8; ++j) {
                const int k = kk*32 + ((lane >> 4) << 3) + j;
                b0[kk][j] = (_Float16)W[(size_t)k * C_OUT + nt0*16 + (lane & 15)];
                b1[kk][j] = (_Float16)W[(size_t)k * C_OUT + nt1*16 + (lane & 15)];
            }
        }
        const float bias0 = bias[nt0*16 + (lane & 15)];
        const float bias1 = bias[nt1*16 + (lane & 15)];
        #pragma unroll 1
        for (int p = 0; p < P_BLK; ++p) {
            const int r = p*16 + (lane & 15);
            const int rowbase = r * ROWB;
            f32x4 acc0 = {0.f,0.f,0.f,0.f}, acc1 = {0.f,0.f,0.f,0.f};
            #pragma unroll
            for (int kk = 0; kk < 8; ++kk) {
                f16x8 a = *(const f16x8*)(Ab + rowbase + kk*64 + ((lane >> 4) << 4));
                acc0 = __builtin_amdgcn_mfma_f32_16x16x32_f16(a, b0[kk], acc0, 0, 0, 0);
                acc1 = __builtin_amdgcn_mfma_f32_16x16x32_f16(a, b1[kk], acc1, 0, 0, 0);
            }
            float v0 = fmaxf(fmaxf(acc0[0], acc0[1]), fmaxf(acc0[2], acc0[3]));
            float v1 = fmaxf(fmaxf(acc1[0], acc1[1]), fmaxf(acc1[2], acc1[3]));
            v0 = fmaxf(v0, __shfl_xor(v0, 16));
            v0 = fmaxf(v0, __shfl_xor(v0, 32));
            v1 = fmaxf(v1, __shfl_xor(v1, 16));
            v1 = fmaxf(v1, __shfl_xor(v1, 32));
            if (lane < 16) {
                out[(size_t)(m0 + p) * C_OUT + nt0*16 + lane] = v0 + bias0;
                out[(size_t)(m0 + p) * C_OUT + nt1*16 + lane] = v1 + bias1;
            }
        }
    }
}

extern "C" void kernel_launch(void* const* d_in, const int* in_sizes, int n_in,
                              void* d_out, int out_size, void* d_ws, size_t ws_size,
                              hipStream_t stream) {
    const float* x     = (const float*)d_in[0];
    const int*   idx   = (const int*)d_in[1];
    const float* gamma = (const float*)d_in[2];
    const float* beta  = (const float*)d_in[3];
    const float* W     = (const float*)d_in[4];
    const float* b     = (const float*)d_in[5];
    float* out = (float*)d_out;

    hipLaunchKernelGGL(fused_gather_ln_gemm_max, dim3(M_PTS / P_BLK), dim3(NTHREADS), 0, stream,
                       x, idx, gamma, beta, W, b, out);
}

// Round 5
// 156.754 us; speedup vs baseline: 10.7707x; 1.4501x over previous
//
#include <hip/hip_runtime.h>

typedef _Float16 f16x8 __attribute__((ext_vector_type(8)));
typedef unsigned short ushort8 __attribute__((ext_vector_type(8)));
typedef float f32x4 __attribute__((ext_vector_type(4)));

#define C_IN     256
#define C_OUT    512
#define M_PTS    25000
#define KNN      16
#define P_BLK    4
#define ROWS     (P_BLK * KNN)   /* 64 */
#define ROWB     528             /* padded row stride in bytes (264 f16) */
#define NTHREADS 256

__device__ __forceinline__ unsigned short f2h(float f) {
    _Float16 h = (_Float16)f;
    return __builtin_bit_cast(unsigned short, h);
}

// Pack W [C_IN][C_OUT] f32 -> f16 in MFMA B-fragment order:
// Wp[nt*4096 + kk*512 + lane*8 + j] = W[(kk*32 + (lane>>4)*8 + j)*C_OUT + nt*16 + (lane&15)]
// (proven index-identical to round 4's passing direct-load B-frags)
__global__ void pack_w_kernel(const float* __restrict__ W, unsigned short* __restrict__ Wp) {
    int t = blockIdx.x * blockDim.x + threadIdx.x;   // 0 .. 131071
    int j    = t & 7;
    int lane = (t >> 3) & 63;
    int kk   = (t >> 9) & 7;
    int nt   = t >> 12;                               // 0..31
    int k = kk * 32 + ((lane >> 4) << 3) + j;
    int n = nt * 16 + (lane & 15);
    Wp[t] = f2h(W[k * C_OUT + n]);
}

__global__ __launch_bounds__(NTHREADS, 4)
void fused_gather_ln_gemm_max(const float* __restrict__ x,
                              const int* __restrict__ idx,
                              const float* __restrict__ gamma,
                              const float* __restrict__ beta,
                              const unsigned short* __restrict__ Wp,
                              const float* __restrict__ bias,
                              float* __restrict__ out) {
    __shared__ char Ab[ROWS * ROWB];   // 33 KiB, f16 A-tile, padded rows, NO swizzle

    const int tid  = threadIdx.x;
    const int lane = tid & 63;
    const int wave = tid >> 6;
    const int m0   = blockIdx.x * P_BLK;

    // ---- Phase 1: gather + LayerNorm -> LDS (f16) ----
    float gm[16], bt[16];
    const int cg = (tid & 15) * 16;
    #pragma unroll
    for (int q = 0; q < 4; ++q) {
        float4 g4 = ((const float4*)(gamma + cg))[q];
        float4 b4 = ((const float4*)(beta  + cg))[q];
        gm[4*q+0] = g4.x; gm[4*q+1] = g4.y; gm[4*q+2] = g4.z; gm[4*q+3] = g4.w;
        bt[4*q+0] = b4.x; bt[4*q+1] = b4.y; bt[4*q+2] = b4.z; bt[4*q+3] = b4.w;
    }
    #pragma unroll
    for (int it = 0; it < ROWS / 16; ++it) {
        const int r  = it * 16 + (tid >> 4);
        const int xr = idx[m0 * KNN + r];
        const float4* xp = (const float4*)(x + (size_t)xr * C_IN) + (tid & 15) * 4;
        float vv[16];
        float s = 0.f, sq = 0.f;
        #pragma unroll
        for (int q = 0; q < 4; ++q) {
            float4 v4 = xp[q];
            vv[4*q+0] = v4.x; vv[4*q+1] = v4.y; vv[4*q+2] = v4.z; vv[4*q+3] = v4.w;
        }
        #pragma unroll
        for (int e = 0; e < 16; ++e) { s += vv[e]; sq += vv[e]*vv[e]; }
        #pragma unroll
        for (int o = 1; o < 16; o <<= 1) {
            s  += __shfl_xor(s, o);
            sq += __shfl_xor(sq, o);
        }
        const float mu  = s * (1.0f/256.0f);
        const float var = sq * (1.0f/256.0f) - mu * mu;
        const float rs  = rsqrtf(var + 1e-5f);
        ushort8 c0, c1;
        #pragma unroll
        for (int e = 0; e < 8; ++e) c0[e] = f2h((vv[e]   - mu)*rs*gm[e]   + bt[e]);
        #pragma unroll
        for (int e = 0; e < 8; ++e) c1[e] = f2h((vv[e+8] - mu)*rs*gm[e+8] + bt[e+8]);
        const int cb = (tid & 15) * 32;
        *(ushort8*)(Ab + r*ROWB + cb)      = c0;
        *(ushort8*)(Ab + r*ROWB + cb + 16) = c1;
    }
    __syncthreads();

    // ---- Phase 2: MFMA GEMM + fused max; B-frags from packed Wp (L2-resident) ----
    #pragma unroll 1
    for (int ntp = 0; ntp < 4; ++ntp) {
        const int nt0 = wave * 8 + ntp * 2;
        const int nt1 = nt0 + 1;
        f16x8 b0[8], b1[8];
        #pragma unroll
        for (int kk = 0; kk < 8; ++kk) {
            b0[kk] = ((const f16x8*)Wp)[(nt0*8 + kk)*64 + lane];
            b1[kk] = ((const f16x8*)Wp)[(nt1*8 + kk)*64 + lane];
        }
        const float bias0 = bias[nt0*16 + (lane & 15)];
        const float bias1 = bias[nt1*16 + (lane & 15)];
        #pragma unroll 1
        for (int p = 0; p < P_BLK; ++p) {
            const int r = p*16 + (lane & 15);
            const int rowbase = r * ROWB;
            f32x4 acc0 = {0.f,0.f,0.f,0.f}, acc1 = {0.f,0.f,0.f,0.f};
            #pragma unroll
            for (int kk = 0; kk < 8; ++kk) {
                f16x8 a = *(const f16x8*)(Ab + rowbase + kk*64 + ((lane >> 4) << 4));
                acc0 = __builtin_amdgcn_mfma_f32_16x16x32_f16(a, b0[kk], acc0, 0, 0, 0);
                acc1 = __builtin_amdgcn_mfma_f32_16x16x32_f16(a, b1[kk], acc1, 0, 0, 0);
            }
            float v0 = fmaxf(fmaxf(acc0[0], acc0[1]), fmaxf(acc0[2], acc0[3]));
            float v1 = fmaxf(fmaxf(acc1[0], acc1[1]), fmaxf(acc1[2], acc1[3]));
            v0 = fmaxf(v0, __shfl_xor(v0, 16));
            v0 = fmaxf(v0, __shfl_xor(v0, 32));
            v1 = fmaxf(v1, __shfl_xor(v1, 16));
            v1 = fmaxf(v1, __shfl_xor(v1, 32));
            if (lane < 16) {
                out[(size_t)(m0 + p) * C_OUT + nt0*16 + lane] = v0 + bias0;
                out[(size_t)(m0 + p) * C_OUT + nt1*16 + lane] = v1 + bias1;
            }
        }
    }
}

extern "C" void kernel_launch(void* const* d_in, const int* in_sizes, int n_in,
                              void* d_out, int out_size, void* d_ws, size_t ws_size,
                              hipStream_t stream) {
    const float* x     = (const float*)d_in[0];
    const int*   idx   = (const int*)d_in[1];
    const float* gamma = (const float*)d_in[2];
    const float* beta  = (const float*)d_in[3];
    const float* W     = (const float*)d_in[4];
    const float* b     = (const float*)d_in[5];
    float* out = (float*)d_out;
    unsigned short* Wp = (unsigned short*)d_ws;   // 256 KiB scratch

    hipLaunchKernelGGL(pack_w_kernel, dim3((C_IN * C_OUT) / 256), dim3(256), 0, stream, W, Wp);
    hipLaunchKernelGGL(fused_gather_ln_gemm_max, dim3(M_PTS / P_BLK), dim3(NTHREADS), 0, stream,
                       x, idx, gamma, beta, Wp, b, out);
}

// Round 8
// 152.777 us; speedup vs baseline: 11.0511x; 1.0260x over previous
//
#include <hip/hip_runtime.h>

typedef _Float16 f16x8 __attribute__((ext_vector_type(8)));
typedef unsigned short ushort8 __attribute__((ext_vector_type(8)));
typedef float f32x4 __attribute__((ext_vector_type(4)));

#define C_IN     256
#define C_OUT    512
#define M_PTS    25000
#define KNN      16
#define P_BLK    4
#define ROWS     (P_BLK * KNN)   /* 64 */
#define ROWB     528             /* padded row stride in bytes (264 f16) */
#define NTHREADS 256

__device__ __forceinline__ unsigned short f2h(float f) {
    _Float16 h = (_Float16)f;
    return __builtin_bit_cast(unsigned short, h);
}

// Pack W [C_IN][C_OUT] f32 -> f16 in MFMA B-fragment order (verified vs round-4 direct load):
// Wp[nt*4096 + kk*512 + lane*8 + j] = W[(kk*32 + (lane>>4)*8 + j)*C_OUT + nt*16 + (lane&15)]
__global__ void pack_w_kernel(const float* __restrict__ W, unsigned short* __restrict__ Wp) {
    int t = blockIdx.x * blockDim.x + threadIdx.x;   // 0 .. 131071
    int j    = t & 7;
    int lane = (t >> 3) & 63;
    int kk   = (t >> 9) & 7;
    int nt   = t >> 12;                               // 0..31
    int k = kk * 32 + ((lane >> 4) << 3) + j;
    int n = nt * 16 + (lane & 15);
    Wp[t] = f2h(W[k * C_OUT + n]);
}

// R5 structure EXACTLY (known-pass), single change: __launch_bounds__(256,4) -> (256,2).
// R5's VGPR=60 proves b0/b1 (64 regs) were NOT resident under the 128-reg cap: the
// compiler re-sank B-loads into the p-loop => ~6.4 GB of L2 B-traffic (~186us) per
// launch. Cap 256 lets B-frags stay resident: L2-B traffic /4.
__global__ __launch_bounds__(NTHREADS, 2)
void fused_gather_ln_gemm_max(const float* __restrict__ x,
                              const int* __restrict__ idx,
                              const float* __restrict__ gamma,
                              const float* __restrict__ beta,
                              const unsigned short* __restrict__ Wp,
                              const float* __restrict__ bias,
                              float* __restrict__ out) {
    __shared__ char Ab[ROWS * ROWB];   // 33 KiB, f16 A-tile, padded rows, NO swizzle

    const int tid  = threadIdx.x;
    const int lane = tid & 63;
    const int wave = tid >> 6;
    const int m0   = blockIdx.x * P_BLK;

    // ---- Phase 1: gather + LayerNorm -> LDS (f16), unchanged from passing rounds ----
    float gm[16], bt[16];
    const int cg = (tid & 15) * 16;
    #pragma unroll
    for (int q = 0; q < 4; ++q) {
        float4 g4 = ((const float4*)(gamma + cg))[q];
        float4 b4 = ((const float4*)(beta  + cg))[q];
        gm[4*q+0] = g4.x; gm[4*q+1] = g4.y; gm[4*q+2] = g4.z; gm[4*q+3] = g4.w;
        bt[4*q+0] = b4.x; bt[4*q+1] = b4.y; bt[4*q+2] = b4.z; bt[4*q+3] = b4.w;
    }
    #pragma unroll
    for (int it = 0; it < ROWS / 16; ++it) {
        const int r  = it * 16 + (tid >> 4);
        const int xr = idx[m0 * KNN + r];
        const float4* xp = (const float4*)(x + (size_t)xr * C_IN) + (tid & 15) * 4;
        float vv[16];
        float s = 0.f, sq = 0.f;
        #pragma unroll
        for (int q = 0; q < 4; ++q) {
            float4 v4 = xp[q];
            vv[4*q+0] = v4.x; vv[4*q+1] = v4.y; vv[4*q+2] = v4.z; vv[4*q+3] = v4.w;
        }
        #pragma unroll
        for (int e = 0; e < 16; ++e) { s += vv[e]; sq += vv[e]*vv[e]; }
        #pragma unroll
        for (int o = 1; o < 16; o <<= 1) {
            s  += __shfl_xor(s, o);
            sq += __shfl_xor(sq, o);
        }
        const float mu  = s * (1.0f/256.0f);
        const float var = sq * (1.0f/256.0f) - mu * mu;
        const float rs  = rsqrtf(var + 1e-5f);
        ushort8 c0, c1;
        #pragma unroll
        for (int e = 0; e < 8; ++e) c0[e] = f2h((vv[e]   - mu)*rs*gm[e]   + bt[e]);
        #pragma unroll
        for (int e = 0; e < 8; ++e) c1[e] = f2h((vv[e+8] - mu)*rs*gm[e+8] + bt[e+8]);
        const int cb = (tid & 15) * 32;
        *(ushort8*)(Ab + r*ROWB + cb)      = c0;
        *(ushort8*)(Ab + r*ROWB + cb + 16) = c1;
    }
    __syncthreads();

    // ---- Phase 2: MFMA GEMM + fused max; 2 col-tiles per group (R5 known-good) ----
    #pragma unroll 1
    for (int ntp = 0; ntp < 4; ++ntp) {
        const int nt0 = wave * 8 + ntp * 2;
        const int nt1 = nt0 + 1;
        f16x8 b0[8], b1[8];
        #pragma unroll
        for (int kk = 0; kk < 8; ++kk) {
            b0[kk] = ((const f16x8*)Wp)[(nt0*8 + kk)*64 + lane];
            b1[kk] = ((const f16x8*)Wp)[(nt1*8 + kk)*64 + lane];
        }
        const float bias0 = bias[nt0*16 + (lane & 15)];
        const float bias1 = bias[nt1*16 + (lane & 15)];
        #pragma unroll 1
        for (int p = 0; p < P_BLK; ++p) {
            const int r = p*16 + (lane & 15);
            const int rowbase = r * ROWB;
            f32x4 acc0 = {0.f,0.f,0.f,0.f}, acc1 = {0.f,0.f,0.f,0.f};
            #pragma unroll
            for (int kk = 0; kk < 8; ++kk) {
                f16x8 a = *(const f16x8*)(Ab + rowbase + kk*64 + ((lane >> 4) << 4));
                acc0 = __builtin_amdgcn_mfma_f32_16x16x32_f16(a, b0[kk], acc0, 0, 0, 0);
                acc1 = __builtin_amdgcn_mfma_f32_16x16x32_f16(a, b1[kk], acc1, 0, 0, 0);
            }
            float v0 = fmaxf(fmaxf(acc0[0], acc0[1]), fmaxf(acc0[2], acc0[3]));
            float v1 = fmaxf(fmaxf(acc1[0], acc1[1]), fmaxf(acc1[2], acc1[3]));
            v0 = fmaxf(v0, __shfl_xor(v0, 16));
            v0 = fmaxf(v0, __shfl_xor(v0, 32));
            v1 = fmaxf(v1, __shfl_xor(v1, 16));
            v1 = fmaxf(v1, __shfl_xor(v1, 32));
            if (lane < 16) {
                out[(size_t)(m0 + p) * C_OUT + nt0*16 + lane] = v0 + bias0;
                out[(size_t)(m0 + p) * C_OUT + nt1*16 + lane] = v1 + bias1;
            }
        }
    }
}

extern "C" void kernel_launch(void* const* d_in, const int* in_sizes, int n_in,
                              void* d_out, int out_size, void* d_ws, size_t ws_size,
                              hipStream_t stream) {
    const float* x     = (const float*)d_in[0];
    const int*   idx   = (const int*)d_in[1];
    const float* gamma = (const float*)d_in[2];
    const float* beta  = (const float*)d_in[3];
    const float* W     = (const float*)d_in[4];
    const float* b     = (const float*)d_in[5];
    float* out = (float*)d_out;
    unsigned short* Wp = (unsigned short*)d_ws;   // 256 KiB scratch

    hipLaunchKernelGGL(pack_w_kernel, dim3((C_IN * C_OUT) / 256), dim3(256), 0, stream, W, Wp);
    hipLaunchKernelGGL(fused_gather_ln_gemm_max, dim3(M_PTS / P_BLK), dim3(NTHREADS), 0, stream,
                       x, idx, gamma, beta, Wp, b, out);
}